// Round 3
// baseline (58.283 us; speedup 1.0000x reference)
//
#include <hip/hip_runtime.h>
#include <hip/hip_bf16.h>

#define BETA_INV 12.5f
#define EPS_NRM 1e-8f
#define NPAIR 4096
#define DDIM 256
#define MROWS 8192   // 2N
#define NTILE 64     // 8192 / 128
#define NBLK (NTILE * (NTILE + 1) / 2)   // 2080 upper-triangle tiles

typedef __attribute__((ext_vector_type(8))) short bf16x8;   // 8 bf16 = 4 VGPRs
typedef __attribute__((ext_vector_type(4))) float f32x4;

// ---------------------------------------------------------------------------
// Kernel 1: row-pair normalize. One wave per pair i: computes ||x1_i||, ||x2_i||,
// x1_i . x2_i in f32; writes zn[i] (bf16), zn[i+N] (bf16), pos_half[i].
// Also zeroes denom[] (first 32 blocks) so no separate memset dispatch.
// ---------------------------------------------------------------------------
__global__ __launch_bounds__(256) void cl_normalize(
    const float* __restrict__ x1, const float* __restrict__ x2,
    ushort* __restrict__ zn, float* __restrict__ pos_half,
    float* __restrict__ denom) {
  if (blockIdx.x < 32) denom[blockIdx.x * 256 + threadIdx.x] = 0.0f;

  int wid  = threadIdx.x >> 6;
  int lane = threadIdx.x & 63;
  int row  = blockIdx.x * 4 + wid;           // pair index in [0, 4096)
  const float4* p1 = (const float4*)(x1 + row * DDIM);
  const float4* p2 = (const float4*)(x2 + row * DDIM);
  float4 a = p1[lane];
  float4 b = p2[lane];
  float s11 = a.x*a.x + a.y*a.y + a.z*a.z + a.w*a.w;
  float s22 = b.x*b.x + b.y*b.y + b.z*b.z + b.w*b.w;
  float s12 = a.x*b.x + a.y*b.y + a.z*b.z + a.w*b.w;
  #pragma unroll
  for (int m = 1; m < 64; m <<= 1) {
    s11 += __shfl_xor(s11, m);
    s22 += __shfl_xor(s22, m);
    s12 += __shfl_xor(s12, m);
  }
  float r1 = fmaxf(sqrtf(s11), EPS_NRM);
  float r2 = fmaxf(sqrtf(s22), EPS_NRM);
  float i1 = 1.0f / r1, i2 = 1.0f / r2;

  union { ushort4 u; __hip_bfloat16 h[4]; } w1, w2;
  w1.h[0] = __float2bfloat16(a.x * i1); w1.h[1] = __float2bfloat16(a.y * i1);
  w1.h[2] = __float2bfloat16(a.z * i1); w1.h[3] = __float2bfloat16(a.w * i1);
  w2.h[0] = __float2bfloat16(b.x * i2); w2.h[1] = __float2bfloat16(b.y * i2);
  w2.h[2] = __float2bfloat16(b.z * i2); w2.h[3] = __float2bfloat16(b.w * i2);
  *(ushort4*)(zn + row * DDIM + lane * 4)            = w1.u;
  *(ushort4*)(zn + (row + NPAIR) * DDIM + lane * 4)  = w2.u;

  if (lane == 0) pos_half[row] = s12 * i1 * i2 * BETA_INV;
}

// ---------------------------------------------------------------------------
// Kernel 2: symmetric Gram tile + exp + masked row/col sums.
// Upper-triangle 128x128 tiles only. Per block:
//   - A fragments (full K=256) preloaded global->VGPR (rows have no
//     cross-wave reuse, so LDS staging of A was pure overhead)
//   - B tile (128 x 256, 64 KB) staged ONCE into LDS via global_load_lds
//     (linear LDS dest, pre-swizzled per-lane global source; 16B-chunk
//     XOR (c&7) -> conflict-free ds_read_b128 of B fragments)
//   - single barrier, then 64 ds_read + 128 MFMA per thread, no syncs
//   - uniform epilogue: exp contributes to denom[row] AND denom[col]
//     iff gcol > grow (handles diagonal and off-diagonal tiles alike)
// ---------------------------------------------------------------------------
__global__ __launch_bounds__(256) void cl_gram_expsum(
    const ushort* __restrict__ zn, float* __restrict__ denom) {
  // decode linear block id -> (i, j) with i <= j in the tile upper triangle
  int idx = blockIdx.x;
  int j = (int)((sqrtf(8.0f * idx + 1.0f) - 1.0f) * 0.5f);
  while ((j + 1) * (j + 2) / 2 <= idx) ++j;
  while (j * (j + 1) / 2 > idx) --j;
  int i = idx - j * (j + 1) / 2;
  int brow = i * 128;
  int bcol = j * 128;

  __shared__ ushort Bs[128 * DDIM];   // 64 KiB: full-K B tile, swizzled

  int tid  = threadIdx.x;
  int wid  = tid >> 6;
  int lane = tid & 63;
  int l15  = lane & 15;
  int lg   = lane >> 4;

  // ---- stage B: 16 x global_load_lds(16B) per wave, each writes 1 KiB
  // lane l covers row c = c0 + (l>>5), stored chunk sc = l&31;
  // source chunk = sc ^ (c&7)  (self-inverse swizzle, applied on read too)
  {
    int c_in  = lane >> 5;          // 0/1: row within this 1KB chunk
    int sc    = lane & 31;          // stored 16B chunk index
    #pragma unroll
    for (int it = 0; it < 16; ++it) {
      int c0 = wid * 32 + it * 2;
      int c  = c0 + c_in;
      int s  = sc ^ (c & 7);
      const ushort* src = zn + (size_t)(bcol + c) * DDIM + s * 8;
      ushort* dst = Bs + c0 * DDIM;          // wave-uniform base
      __builtin_amdgcn_global_load_lds(
          (const __attribute__((address_space(1))) unsigned int*)src,
          (__attribute__((address_space(3))) unsigned int*)dst, 16, 0, 0);
    }
  }

  // ---- A fragments: full-K, direct from global (L2-resident)
  bf16x8 af[2][8];
  #pragma unroll
  for (int rt = 0; rt < 2; ++rt) {
    int r = brow + 32 * wid + 16 * rt + l15;
    const ushort* arow = zn + (size_t)r * DDIM + lg * 8;
    #pragma unroll
    for (int ks = 0; ks < 8; ++ks)
      af[rt][ks] = *(const bf16x8*)(arow + ks * 32);
  }

  f32x4 acc[2][8];
  #pragma unroll
  for (int rt = 0; rt < 2; ++rt)
    #pragma unroll
    for (int ct = 0; ct < 8; ++ct)
      acc[rt][ct] = (f32x4){0.f, 0.f, 0.f, 0.f};

  __syncthreads();   // compiler emits vmcnt(0) drain: B tile + A frags ready

  // ---- main compute: no further barriers
  #pragma unroll
  for (int ks = 0; ks < 8; ++ks) {
    bf16x8 bfv[8];
    #pragma unroll
    for (int ct = 0; ct < 8; ++ct) {
      int c  = 16 * ct + l15;
      int ch = (4 * ks + lg) ^ (c & 7);      // swizzled 16B chunk
      bfv[ct] = *(const bf16x8*)(Bs + c * DDIM + ch * 8);
    }
    #pragma unroll
    for (int rt = 0; rt < 2; ++rt)
      #pragma unroll
      for (int ct = 0; ct < 8; ++ct)
        acc[rt][ct] = __builtin_amdgcn_mfma_f32_16x16x32_bf16(
            af[rt][ks], bfv[ct], acc[rt][ct], 0, 0, 0);
  }

  __syncthreads();   // everyone done reading Bs (reused for col reduction)

  // ---- epilogue: e = exp(sim/beta) iff gcol > grow; feeds row AND col sums
  float csum[8];
  #pragma unroll
  for (int ct = 0; ct < 8; ++ct) csum[ct] = 0.f;

  #pragma unroll
  for (int rt = 0; rt < 2; ++rt) {
    int grow_base = brow + 32 * wid + 16 * rt + lg * 4;
    #pragma unroll
    for (int reg = 0; reg < 4; ++reg) {
      int grow = grow_base + reg;
      float s = 0.f;
      #pragma unroll
      for (int ct = 0; ct < 8; ++ct) {
        int gcol = bcol + 16 * ct + l15;
        float e = __expf(acc[rt][ct][reg] * BETA_INV);
        e = (gcol > grow) ? e : 0.f;
        s += e;
        csum[ct] += e;
      }
      s += __shfl_xor(s, 1);
      s += __shfl_xor(s, 2);
      s += __shfl_xor(s, 4);
      s += __shfl_xor(s, 8);
      if (l15 == 0) atomicAdd(&denom[grow], s);
    }
  }

  // col-sums: reduce across lane-groups (rows) in-wave, then across the
  // 4 waves via LDS (reusing Bs), then 128 atomics.
  float* colred = (float*)Bs;        // [4][128] floats = 2 KiB
  #pragma unroll
  for (int ct = 0; ct < 8; ++ct) {
    float c = csum[ct];
    c += __shfl_xor(c, 16);
    c += __shfl_xor(c, 32);
    if (lg == 0) colred[wid * 128 + ct * 16 + l15] = c;
  }
  __syncthreads();
  if (tid < 128) {
    float c = colred[tid] + colred[128 + tid] + colred[256 + tid] +
              colred[384 + tid];
    atomicAdd(&denom[bcol + tid], c);
  }
}

// ---------------------------------------------------------------------------
// Kernel 3: loss = (sum_i log(denom_i) - 2 * sum_i pos_half_i) / 8192
// ---------------------------------------------------------------------------
__global__ __launch_bounds__(1024) void cl_finalize(
    const float* __restrict__ denom, const float* __restrict__ pos_half,
    float* __restrict__ out) {
  float s = 0.f, p = 0.f;
  for (int i = threadIdx.x; i < MROWS; i += 1024) s += logf(denom[i]);
  for (int i = threadIdx.x; i < NPAIR; i += 1024) p += pos_half[i];
  #pragma unroll
  for (int m = 1; m < 64; m <<= 1) {
    s += __shfl_xor(s, m);
    p += __shfl_xor(p, m);
  }
  __shared__ float red[2][16];
  int wid = threadIdx.x >> 6, lane = threadIdx.x & 63;
  if (lane == 0) { red[0][wid] = s; red[1][wid] = p; }
  __syncthreads();
  if (threadIdx.x == 0) {
    float S = 0.f, P = 0.f;
    #pragma unroll
    for (int w = 0; w < 16; ++w) { S += red[0][w]; P += red[1][w]; }
    out[0] = (S - 2.f * P) / (float)MROWS;
  }
}

extern "C" void kernel_launch(void* const* d_in, const int* in_sizes, int n_in,
                              void* d_out, int out_size, void* d_ws, size_t ws_size,
                              hipStream_t stream) {
  const float* x1 = (const float*)d_in[0];
  const float* x2 = (const float*)d_in[1];
  float* out = (float*)d_out;

  char* ws = (char*)d_ws;
  ushort* zn      = (ushort*)ws;                                 // 4 MiB bf16
  float*  denom   = (float*)(ws + (size_t)MROWS * DDIM * 2);     // 32 KiB
  float*  posh    = (float*)(ws + (size_t)MROWS * DDIM * 2 + MROWS * 4);

  cl_normalize<<<NPAIR / 4, 256, 0, stream>>>(x1, x2, zn, posh, denom);
  cl_gram_expsum<<<NBLK, 256, 0, stream>>>(zn, denom);
  cl_finalize<<<1, 1024, 0, stream>>>(denom, posh, out);
}

// Round 5
// 57.832 us; speedup vs baseline: 1.0078x; 1.0078x over previous
//
#include <hip/hip_runtime.h>
#include <hip/hip_bf16.h>

#define BETA_INV 12.5f
#define EPS_NRM 1e-8f
#define NPAIR 4096
#define DDIM 256
#define MROWS 8192   // 2N
#define NTILE 64     // 8192 / 128
#define NBLK (NTILE * (NTILE + 1) / 2)   // 2080 upper-triangle tiles

typedef __attribute__((ext_vector_type(8))) short bf16x8;   // 8 bf16 = 4 VGPRs
typedef __attribute__((ext_vector_type(4))) float f32x4;

// ---------------------------------------------------------------------------
// Kernel 1: row-pair normalize (verified rounds 1-3). One wave per pair.
// Also zeroes denom[] so no separate memset dispatch.
// ---------------------------------------------------------------------------
__global__ __launch_bounds__(256) void cl_normalize(
    const float* __restrict__ x1, const float* __restrict__ x2,
    ushort* __restrict__ zn, float* __restrict__ pos_half,
    float* __restrict__ denom) {
  if (blockIdx.x < 32) denom[blockIdx.x * 256 + threadIdx.x] = 0.0f;

  int wid  = threadIdx.x >> 6;
  int lane = threadIdx.x & 63;
  int row  = blockIdx.x * 4 + wid;           // pair index in [0, 4096)
  const float4* p1 = (const float4*)(x1 + row * DDIM);
  const float4* p2 = (const float4*)(x2 + row * DDIM);
  float4 a = p1[lane];
  float4 b = p2[lane];
  float s11 = a.x*a.x + a.y*a.y + a.z*a.z + a.w*a.w;
  float s22 = b.x*b.x + b.y*b.y + b.z*b.z + b.w*b.w;
  float s12 = a.x*b.x + a.y*b.y + a.z*b.z + a.w*b.w;
  #pragma unroll
  for (int m = 1; m < 64; m <<= 1) {
    s11 += __shfl_xor(s11, m);
    s22 += __shfl_xor(s22, m);
    s12 += __shfl_xor(s12, m);
  }
  float r1 = fmaxf(sqrtf(s11), EPS_NRM);
  float r2 = fmaxf(sqrtf(s22), EPS_NRM);
  float i1 = 1.0f / r1, i2 = 1.0f / r2;

  union { ushort4 u; __hip_bfloat16 h[4]; } w1, w2;
  w1.h[0] = __float2bfloat16(a.x * i1); w1.h[1] = __float2bfloat16(a.y * i1);
  w1.h[2] = __float2bfloat16(a.z * i1); w1.h[3] = __float2bfloat16(a.w * i1);
  w2.h[0] = __float2bfloat16(b.x * i2); w2.h[1] = __float2bfloat16(b.y * i2);
  w2.h[2] = __float2bfloat16(b.z * i2); w2.h[3] = __float2bfloat16(b.w * i2);
  *(ushort4*)(zn + row * DDIM + lane * 4)            = w1.u;
  *(ushort4*)(zn + (row + NPAIR) * DDIM + lane * 4)  = w2.u;

  if (lane == 0) pos_half[row] = s12 * i1 * i2 * BETA_INV;
}

// ---------------------------------------------------------------------------
// Kernel 2: symmetric Gram tile + exp + row/col sums.
// Upper-triangle 128x128 tiles. Per K-chunk (BK=64, 4 chunks), the VERIFIED
// m97/round-2 schedule: stage -> sync -> compute -> sync. No cross-barrier
// in-flight DMA (round 4's pipeline NaN'd - sync-structure edits need race
// screening; this round uses only orderings already proven on this problem).
//   - B chunk in LDS [128][64] (16 KB single buffer; the layout that
//     measured ZERO bank conflicts in round 2), staged via global_load_lds
//     with pre-swizzled source (s = (lane&7) ^ rlo, self-inverse on read)
//   - A global->reg per chunk (16 VGPR, consumed immediately after the sync)
//   - uniform epilogue (verified round 3): exp feeds denom[row] AND
//     denom[col] iff gcol > grow (covers diagonal + off-diagonal tiles)
// ---------------------------------------------------------------------------
__global__ __launch_bounds__(256) void cl_gram_expsum(
    const ushort* __restrict__ zn, float* __restrict__ denom) {
  // decode linear block id -> (i, j) with i <= j in the tile upper triangle
  int idx = blockIdx.x;
  int j = (int)((sqrtf(8.0f * idx + 1.0f) - 1.0f) * 0.5f);
  while ((j + 1) * (j + 2) / 2 <= idx) ++j;
  while (j * (j + 1) / 2 > idx) --j;
  int i = idx - j * (j + 1) / 2;
  int brow = i * 128;
  int bcol = j * 128;

  __shared__ ushort Bs[128][64];   // 16 KiB B chunk, swizzled rows

  int tid  = threadIdx.x;
  int wid  = tid >> 6;
  int lane = tid & 63;
  int l15  = lane & 15;
  int lg   = lane >> 4;

  f32x4 acc[2][8];
  #pragma unroll
  for (int rt = 0; rt < 2; ++rt)
    #pragma unroll
    for (int ct = 0; ct < 8; ++ct)
      acc[rt][ct] = (f32x4){0.f, 0.f, 0.f, 0.f};

  for (int kc = 0; kc < 4; ++kc) {
    // ---- stage B chunk kc: 4 x global_load_lds(16B) per wave, 8 rows each.
    // Linear LDS dest (wave base + lane*16B); lane covers row r0+(lane>>3),
    // stored chunk (lane&7); source chunk pre-swizzled s = (lane&7) ^ rlo
    // so that LDS(r, ch) holds global chunk ch ^ (r&7)  (self-inverse).
    {
      int rlo = lane >> 3;
      int s   = (lane & 7) ^ rlo;
      #pragma unroll
      for (int it = 0; it < 4; ++it) {
        int r0 = wid * 32 + it * 8;
        const ushort* src =
            zn + (size_t)(bcol + r0 + rlo) * DDIM + kc * 64 + s * 8;
        __builtin_amdgcn_global_load_lds(
            (const __attribute__((address_space(1))) unsigned int*)src,
            (__attribute__((address_space(3))) unsigned int*)&Bs[r0][0],
            16, 0, 0);
      }
    }

    // ---- A fragments for chunk kc: global -> registers (L2-resident),
    // issued before the sync so L2 latency overlaps the barrier drain.
    bf16x8 areg[2][2];
    #pragma unroll
    for (int rt = 0; rt < 2; ++rt) {
      int r = brow + 32 * wid + 16 * rt + l15;
      #pragma unroll
      for (int ks = 0; ks < 2; ++ks)
        areg[rt][ks] = *(const bf16x8*)(zn + (size_t)r * DDIM + kc * 64 +
                                        ks * 32 + lg * 8);
    }

    __syncthreads();   // vmcnt(0) drain: B chunk in LDS, A frags in regs

    // ---- compute chunk: 16 ds_read_b128 + 32 MFMA per thread
    #pragma unroll
    for (int ks = 0; ks < 2; ++ks) {
      bf16x8 bfv[8];
      #pragma unroll
      for (int ct = 0; ct < 8; ++ct) {
        int c  = 16 * ct + l15;
        int su = (4 * ks + lg) ^ (l15 & 7);   // = kslot ^ (c&7)
        bfv[ct] = *(const bf16x8*)&Bs[c][su * 8];
      }
      #pragma unroll
      for (int rt = 0; rt < 2; ++rt)
        #pragma unroll
        for (int ct = 0; ct < 8; ++ct)
          acc[rt][ct] = __builtin_amdgcn_mfma_f32_16x16x32_bf16(
              areg[rt][ks], bfv[ct], acc[rt][ct], 0, 0, 0);
    }

    __syncthreads();   // all waves done reading Bs before next stage
  }

  // ---- epilogue: e = exp(sim/beta) iff gcol > grow; feeds row AND col sums
  float csum[8];
  #pragma unroll
  for (int ct = 0; ct < 8; ++ct) csum[ct] = 0.f;

  #pragma unroll
  for (int rt = 0; rt < 2; ++rt) {
    int grow_base = brow + 32 * wid + 16 * rt + lg * 4;
    #pragma unroll
    for (int reg = 0; reg < 4; ++reg) {
      int grow = grow_base + reg;
      float s = 0.f;
      #pragma unroll
      for (int ct = 0; ct < 8; ++ct) {
        int gcol = bcol + 16 * ct + l15;
        float e = __expf(acc[rt][ct][reg] * BETA_INV);
        e = (gcol > grow) ? e : 0.f;
        s += e;
        csum[ct] += e;
      }
      s += __shfl_xor(s, 1);
      s += __shfl_xor(s, 2);
      s += __shfl_xor(s, 4);
      s += __shfl_xor(s, 8);
      if (l15 == 0) atomicAdd(&denom[grow], s);
    }
  }

  // col-sums: reduce across lane-groups (rows) in-wave, then across the
  // 4 waves via LDS (reusing Bs), then 128 atomics.
  float* colred = (float*)Bs;        // [4][128] floats = 2 KiB
  #pragma unroll
  for (int ct = 0; ct < 8; ++ct) {
    float c = csum[ct];
    c += __shfl_xor(c, 16);
    c += __shfl_xor(c, 32);
    if (lg == 0) colred[wid * 128 + ct * 16 + l15] = c;
  }
  __syncthreads();
  if (tid < 128) {
    float c = colred[tid] + colred[128 + tid] + colred[256 + tid] +
              colred[384 + tid];
    atomicAdd(&denom[bcol + tid], c);
  }
}

// ---------------------------------------------------------------------------
// Kernel 3: loss = (sum_i log(denom_i) - 2 * sum_i pos_half_i) / 8192
// ---------------------------------------------------------------------------
__global__ __launch_bounds__(1024) void cl_finalize(
    const float* __restrict__ denom, const float* __restrict__ pos_half,
    float* __restrict__ out) {
  float s = 0.f, p = 0.f;
  for (int i = threadIdx.x; i < MROWS; i += 1024) s += logf(denom[i]);
  for (int i = threadIdx.x; i < NPAIR; i += 1024) p += pos_half[i];
  #pragma unroll
  for (int m = 1; m < 64; m <<= 1) {
    s += __shfl_xor(s, m);
    p += __shfl_xor(p, m);
  }
  __shared__ float red[2][16];
  int wid = threadIdx.x >> 6, lane = threadIdx.x & 63;
  if (lane == 0) { red[0][wid] = s; red[1][wid] = p; }
  __syncthreads();
  if (threadIdx.x == 0) {
    float S = 0.f, P = 0.f;
    #pragma unroll
    for (int w = 0; w < 16; ++w) { S += red[0][w]; P += red[1][w]; }
    out[0] = (S - 2.f * P) / (float)MROWS;
  }
}

extern "C" void kernel_launch(void* const* d_in, const int* in_sizes, int n_in,
                              void* d_out, int out_size, void* d_ws, size_t ws_size,
                              hipStream_t stream) {
  const float* x1 = (const float*)d_in[0];
  const float* x2 = (const float*)d_in[1];
  float* out = (float*)d_out;

  char* ws = (char*)d_ws;
  ushort* zn      = (ushort*)ws;                                 // 4 MiB bf16
  float*  denom   = (float*)(ws + (size_t)MROWS * DDIM * 2);     // 32 KiB
  float*  posh    = (float*)(ws + (size_t)MROWS * DDIM * 2 + MROWS * 4);

  cl_normalize<<<NPAIR / 4, 256, 0, stream>>>(x1, x2, zn, posh, denom);
  cl_gram_expsum<<<NBLK, 256, 0, stream>>>(zn, denom);
  cl_finalize<<<1, 1024, 0, stream>>>(denom, posh, out);
}

// Round 6
// 55.097 us; speedup vs baseline: 1.0578x; 1.0496x over previous
//
#include <hip/hip_runtime.h>
#include <hip/hip_bf16.h>

#define BETA_INV 12.5f
#define EPS_NRM 1e-8f
#define NPAIR 4096
#define DDIM 256
#define MROWS 8192   // 2N
#define NTILE 64     // 8192 / 128
#define NBLK (NTILE * (NTILE + 1) / 2)   // 2080 upper-triangle tiles

typedef __attribute__((ext_vector_type(8))) short bf16x8;   // 8 bf16 = 4 VGPRs
typedef __attribute__((ext_vector_type(4))) float f32x4;

// ---------------------------------------------------------------------------
// Kernel 1: row-pair normalize (verified). One wave per pair.
// Also zeroes denom[] so no separate memset dispatch.
// ---------------------------------------------------------------------------
__global__ __launch_bounds__(256) void cl_normalize(
    const float* __restrict__ x1, const float* __restrict__ x2,
    ushort* __restrict__ zn, float* __restrict__ pos_half,
    float* __restrict__ denom) {
  if (blockIdx.x < 32) denom[blockIdx.x * 256 + threadIdx.x] = 0.0f;

  int wid  = threadIdx.x >> 6;
  int lane = threadIdx.x & 63;
  int row  = blockIdx.x * 4 + wid;           // pair index in [0, 4096)
  const float4* p1 = (const float4*)(x1 + row * DDIM);
  const float4* p2 = (const float4*)(x2 + row * DDIM);
  float4 a = p1[lane];
  float4 b = p2[lane];
  float s11 = a.x*a.x + a.y*a.y + a.z*a.z + a.w*a.w;
  float s22 = b.x*b.x + b.y*b.y + b.z*b.z + b.w*b.w;
  float s12 = a.x*b.x + a.y*b.y + a.z*b.z + a.w*b.w;
  #pragma unroll
  for (int m = 1; m < 64; m <<= 1) {
    s11 += __shfl_xor(s11, m);
    s22 += __shfl_xor(s22, m);
    s12 += __shfl_xor(s12, m);
  }
  float r1 = fmaxf(sqrtf(s11), EPS_NRM);
  float r2 = fmaxf(sqrtf(s22), EPS_NRM);
  float i1 = 1.0f / r1, i2 = 1.0f / r2;

  union { ushort4 u; __hip_bfloat16 h[4]; } w1, w2;
  w1.h[0] = __float2bfloat16(a.x * i1); w1.h[1] = __float2bfloat16(a.y * i1);
  w1.h[2] = __float2bfloat16(a.z * i1); w1.h[3] = __float2bfloat16(a.w * i1);
  w2.h[0] = __float2bfloat16(b.x * i2); w2.h[1] = __float2bfloat16(b.y * i2);
  w2.h[2] = __float2bfloat16(b.z * i2); w2.h[3] = __float2bfloat16(b.w * i2);
  *(ushort4*)(zn + row * DDIM + lane * 4)            = w1.u;
  *(ushort4*)(zn + (row + NPAIR) * DDIM + lane * 4)  = w2.u;

  if (lane == 0) pos_half[row] = s12 * i1 * i2 * BETA_INV;
}

// ---------------------------------------------------------------------------
// Kernel 2: symmetric Gram tile + exp + row/col sums.
// Upper-triangle 128x128 tiles. Round-5 post-mortem showed ~1.3 blocks/CU
// achieved residency -> barrier drains are fully exposed serial time. So:
// minimize the serial chain: stage the FULL-K B panel (64 KB) as one DMA
// batch -> ONE drain+barrier -> one straight-line compute region (no syncs).
//   - B in LDS [4][128][64]: K-chunked so each row is 128 B = the geometry
//     that measured ZERO bank conflicts (rounds 2/5). Same self-inverse
//     source-chunk XOR (s = (lane&7) ^ rlo) per chunk.
//   - A global->reg per chunk INSIDE the straight-line region (round-5
//     pattern); no barriers between chunks, so the compiler can hoist the
//     loads as far as registers allow. __launch_bounds__(256,2) relaxes
//     the allocator (round 3's remat came from a tight occupancy target).
//   - uniform epilogue (verified): exp feeds denom[row] AND denom[col]
//     iff gcol > grow.
// ---------------------------------------------------------------------------
__global__ __launch_bounds__(256, 2) void cl_gram_expsum(
    const ushort* __restrict__ zn, float* __restrict__ denom) {
  // decode linear block id -> (i, j) with i <= j in the tile upper triangle
  int idx = blockIdx.x;
  int j = (int)((sqrtf(8.0f * idx + 1.0f) - 1.0f) * 0.5f);
  while ((j + 1) * (j + 2) / 2 <= idx) ++j;
  while (j * (j + 1) / 2 > idx) --j;
  int i = idx - j * (j + 1) / 2;
  int brow = i * 128;
  int bcol = j * 128;

  __shared__ ushort Bs[4][128][64];   // 64 KiB: full-K B panel, K-chunked

  int tid  = threadIdx.x;
  int wid  = tid >> 6;
  int lane = tid & 63;
  int l15  = lane & 15;
  int lg   = lane >> 4;

  // ---- stage ALL of B: 16 DMAs per wave (4 chunks x 4), one batch.
  // Per DMA: wave writes 1 KiB linear (8 rows x 128 B); lane covers row
  // r0+(lane>>3), stored chunk (lane&7); source chunk s = (lane&7) ^ rlo
  // so LDS(r, ch) holds global chunk ch ^ (r&7)  (self-inverse swizzle).
  {
    int rlo = lane >> 3;
    int s   = (lane & 7) ^ rlo;
    #pragma unroll
    for (int kc = 0; kc < 4; ++kc) {
      #pragma unroll
      for (int it = 0; it < 4; ++it) {
        int r0 = wid * 32 + it * 8;
        const ushort* src =
            zn + (size_t)(bcol + r0 + rlo) * DDIM + kc * 64 + s * 8;
        __builtin_amdgcn_global_load_lds(
            (const __attribute__((address_space(1))) unsigned int*)src,
            (__attribute__((address_space(3))) unsigned int*)&Bs[kc][r0][0],
            16, 0, 0);
      }
    }
  }

  f32x4 acc[2][8];
  #pragma unroll
  for (int rt = 0; rt < 2; ++rt)
    #pragma unroll
    for (int ct = 0; ct < 8; ++ct)
      acc[rt][ct] = (f32x4){0.f, 0.f, 0.f, 0.f};

  __syncthreads();   // single vmcnt(0) drain: whole B panel resident

  // ---- straight-line compute: 4 chunks, no synchronization anywhere
  #pragma unroll
  for (int kc = 0; kc < 4; ++kc) {
    bf16x8 areg[2][2];
    #pragma unroll
    for (int rt = 0; rt < 2; ++rt) {
      int r = brow + 32 * wid + 16 * rt + l15;
      #pragma unroll
      for (int ks = 0; ks < 2; ++ks)
        areg[rt][ks] = *(const bf16x8*)(zn + (size_t)r * DDIM + kc * 64 +
                                        ks * 32 + lg * 8);
    }
    #pragma unroll
    for (int ks = 0; ks < 2; ++ks) {
      bf16x8 bfv[8];
      #pragma unroll
      for (int ct = 0; ct < 8; ++ct) {
        int c  = 16 * ct + l15;
        int su = (4 * ks + lg) ^ (l15 & 7);   // = kslot ^ (c&7)
        bfv[ct] = *(const bf16x8*)&Bs[kc][c][su * 8];
      }
      #pragma unroll
      for (int rt = 0; rt < 2; ++rt)
        #pragma unroll
        for (int ct = 0; ct < 8; ++ct)
          acc[rt][ct] = __builtin_amdgcn_mfma_f32_16x16x32_bf16(
              areg[rt][ks], bfv[ct], acc[rt][ct], 0, 0, 0);
    }
  }

  // ---- epilogue: e = exp(sim/beta) iff gcol > grow; feeds row AND col sums
  float csum[8];
  #pragma unroll
  for (int ct = 0; ct < 8; ++ct) csum[ct] = 0.f;

  #pragma unroll
  for (int rt = 0; rt < 2; ++rt) {
    int grow_base = brow + 32 * wid + 16 * rt + lg * 4;
    #pragma unroll
    for (int reg = 0; reg < 4; ++reg) {
      int grow = grow_base + reg;
      float s = 0.f;
      #pragma unroll
      for (int ct = 0; ct < 8; ++ct) {
        int gcol = bcol + 16 * ct + l15;
        float e = __expf(acc[rt][ct][reg] * BETA_INV);
        e = (gcol > grow) ? e : 0.f;
        s += e;
        csum[ct] += e;
      }
      s += __shfl_xor(s, 1);
      s += __shfl_xor(s, 2);
      s += __shfl_xor(s, 4);
      s += __shfl_xor(s, 8);
      if (l15 == 0) atomicAdd(&denom[grow], s);
    }
  }

  __syncthreads();   // all waves done reading Bs (reused for col reduction)

  // col-sums: reduce across lane-groups (rows) in-wave, then across the
  // 4 waves via LDS (reusing Bs), then 128 atomics.
  float* colred = (float*)Bs;        // [4][128] floats = 2 KiB
  #pragma unroll
  for (int ct = 0; ct < 8; ++ct) {
    float c = csum[ct];
    c += __shfl_xor(c, 16);
    c += __shfl_xor(c, 32);
    if (lg == 0) colred[wid * 128 + ct * 16 + l15] = c;
  }
  __syncthreads();
  if (tid < 128) {
    float c = colred[tid] + colred[128 + tid] + colred[256 + tid] +
              colred[384 + tid];
    atomicAdd(&denom[bcol + tid], c);
  }
}

// ---------------------------------------------------------------------------
// Kernel 3: loss = (sum_i log(denom_i) - 2 * sum_i pos_half_i) / 8192
// ---------------------------------------------------------------------------
__global__ __launch_bounds__(1024) void cl_finalize(
    const float* __restrict__ denom, const float* __restrict__ pos_half,
    float* __restrict__ out) {
  float s = 0.f, p = 0.f;
  for (int i = threadIdx.x; i < MROWS; i += 1024) s += logf(denom[i]);
  for (int i = threadIdx.x; i < NPAIR; i += 1024) p += pos_half[i];
  #pragma unroll
  for (int m = 1; m < 64; m <<= 1) {
    s += __shfl_xor(s, m);
    p += __shfl_xor(p, m);
  }
  __shared__ float red[2][16];
  int wid = threadIdx.x >> 6, lane = threadIdx.x & 63;
  if (lane == 0) { red[0][wid] = s; red[1][wid] = p; }
  __syncthreads();
  if (threadIdx.x == 0) {
    float S = 0.f, P = 0.f;
    #pragma unroll
    for (int w = 0; w < 16; ++w) { S += red[0][w]; P += red[1][w]; }
    out[0] = (S - 2.f * P) / (float)MROWS;
  }
}

extern "C" void kernel_launch(void* const* d_in, const int* in_sizes, int n_in,
                              void* d_out, int out_size, void* d_ws, size_t ws_size,
                              hipStream_t stream) {
  const float* x1 = (const float*)d_in[0];
  const float* x2 = (const float*)d_in[1];
  float* out = (float*)d_out;

  char* ws = (char*)d_ws;
  ushort* zn      = (ushort*)ws;                                 // 4 MiB bf16
  float*  denom   = (float*)(ws + (size_t)MROWS * DDIM * 2);     // 32 KiB
  float*  posh    = (float*)(ws + (size_t)MROWS * DDIM * 2 + MROWS * 4);

  cl_normalize<<<NPAIR / 4, 256, 0, stream>>>(x1, x2, zn, posh, denom);
  cl_gram_expsum<<<NBLK, 256, 0, stream>>>(zn, denom);
  cl_finalize<<<1, 1024, 0, stream>>>(denom, posh, out);
}